// Round 12
// baseline (292.216 us; speedup 1.0000x reference)
//
#include <hip/hip_runtime.h>
#include <math.h>

// approxmatch EMD (Fan et al.) — b=8, n=m=2048, f32.
// R12 = R11 + RPW 8 (8 rows/wave, ILP x2) + explicit depth-1 LDS prefetch.
// 22 dispatches: A0(+pack) | 10 x { B_t ; CA_t } | cost.
// Level t: kk_t = -4^(7-t)*L2E (t<=8), kk_9 = 0.
//   A: f_i = multiL/(1e-9 + multiR*sum_j e(kk))          [level 0]
//   B: s_j = sum_i f_i e(kk); colsum=R s; rr=min(R/(1e-9+colsum),1);
//      c=R rr; R' = max(R-colsum rr,0)
//   C: t_i=sum_j c e; u_i=sum_j c e sqrt(d2);
//      remL'=max(remL-f t,0); cost+=f u
// CA_t fuses C_t with A_{t+1} (level_t = 4*level_{t+1} exact for t<8):
// e1=exp2(kk_{t+1} d2) serves C (e1^4) and A (e1).
// Folded exponent: kk*d2 = kk|p|^2 + kk|q|^2 - 2kk(p.q);
// sqrt(d2)=sqrt(|kk d2|)/sqrt(|kk|) hoisted. Rows packed in v2 pairs.

#define NPTS 2048
#define BLOCK 256
#define RPW 8                // rows per wave
#define RPB 32               // rows per block (4 waves x 8) -> grid 512
#define L2E 1.4426950408889634f

typedef float v2 __attribute__((ext_vector_type(2)));

__device__ __forceinline__ float fexp2(float x) { return __builtin_amdgcn_exp2f(x); }
__device__ __forceinline__ float fsqrt(float x) { return __builtin_amdgcn_sqrtf(x); }
__device__ __forceinline__ v2 fma2(v2 a, v2 b, v2 c) { return __builtin_elementwise_fma(a, b, c); }
__device__ __forceinline__ v2 sp(float a) { v2 r; r.x = a; r.y = a; return r; }
__device__ __forceinline__ float xreduce(float v) {
#pragma unroll
    for (int off = 1; off < 64; off <<= 1) v += __shfl_xor(v, off, 64);
    return v;
}

struct RowPair { v2 pa, px, py, pz; };
__device__ __forceinline__ RowPair mk_pair(float4 a, float4 b, float kp) {
    RowPair r;
    r.pa = v2{kp * a.w, kp * b.w};
    r.px = v2{-2.f*kp*a.x, -2.f*kp*b.x};
    r.py = v2{-2.f*kp*a.y, -2.f*kp*b.y};
    r.pz = v2{-2.f*kp*a.z, -2.f*kp*b.z};
    return r;
}
__device__ __forceinline__ v2 term(const RowPair& r, float qx, float qy, float qz, v2 qb2) {
    return fma2(r.px, sp(qx), fma2(r.py, sp(qy), fma2(r.pz, sp(qz), r.pa + qb2)));
}
__device__ __forceinline__ float4 with_sq(float4 p) {
    p.w = p.x*p.x + p.y*p.y + p.z*p.z;
    return p;
}

// Level-0 rows pass; packs this block's 32 rows/cols into float4 arrays.
__global__ __launch_bounds__(BLOCK) void k_A(
    const float* __restrict__ xyz1, const float* __restrict__ xyz2,
    float4* __restrict__ p1w, float4* __restrict__ p2w,
    float* __restrict__ f_g, float kk, float multiL, float multiR)
{
    __shared__ float4 sQ[NPTS];              // x,y,z, kk*|q|^2
    const int row0 = blockIdx.x * RPB;
    const int batch = row0 >> 11;
    const int rloc = row0 & 2047;
    const float* g1 = xyz1 + (size_t)batch * NPTS * 3;
    const float* g2 = xyz2 + (size_t)batch * NPTS * 3;
    if (threadIdx.x < RPB) {
        int i = rloc + threadIdx.x;
        p1w[((size_t)batch << 11) + i] = make_float4(g1[3*i], g1[3*i+1], g1[3*i+2], 0.f);
    } else if (threadIdx.x < 2 * RPB) {
        int i = rloc + threadIdx.x - RPB;
        p2w[((size_t)batch << 11) + i] = make_float4(g2[3*i], g2[3*i+1], g2[3*i+2], 0.f);
    }
    for (int j = threadIdx.x; j < NPTS; j += BLOCK) {
        float qx = g2[3*j], qy = g2[3*j+1], qz = g2[3*j+2];
        sQ[j] = make_float4(qx, qy, qz, kk * (qx*qx + qy*qy + qz*qz));
    }
    __syncthreads();
    const int lane = threadIdx.x & 63;
    const int wave = threadIdx.x >> 6;
    const int r0 = row0 + wave * RPW;
    RowPair rp[4];
#pragma unroll
    for (int k = 0; k < 4; ++k) {
        const float* p = g1 + 3 * ((r0 & 2047) + 2 * k);
        float4 a = make_float4(p[0], p[1], p[2], p[0]*p[0]+p[1]*p[1]+p[2]*p[2]);
        float4 b = make_float4(p[3], p[4], p[5], p[3]*p[3]+p[4]*p[4]+p[5]*p[5]);
        rp[k] = mk_pair(a, b, kk);
    }
    v2 aS[4];
#pragma unroll
    for (int k = 0; k < 4; ++k) aS[k] = sp(0.f);
    float4 qc = sQ[lane];
#pragma unroll 1
    for (int it = 0; it < NPTS / 64; ++it) {
        float4 qn = sQ[(lane + (it + 1) * 64) & 2047];
        v2 qb2 = sp(qc.w);
#pragma unroll
        for (int k = 0; k < 4; ++k) {
            v2 t = term(rp[k], qc.x, qc.y, qc.z, qb2);
            aS[k] += v2{fexp2(t.x), fexp2(t.y)};
        }
        qc = qn;
    }
    if (lane == 0) { /* placeholder to keep structure clear */ }
    float sv[RPW];
#pragma unroll
    for (int k = 0; k < 4; ++k) {
        sv[2*k]   = xreduce(aS[k].x);
        sv[2*k+1] = xreduce(aS[k].y);
    }
    if (lane == 0) {
#pragma unroll
        for (int r = 0; r < RPW; ++r)
            f_g[r0 + r] = multiL / (1e-9f + multiR * sv[r]);
    }
}

// Cols pass. LDS 40KB.
template <bool FIRST>
__global__ __launch_bounds__(BLOCK) void k_B(
    const float4* __restrict__ p1w, const float4* __restrict__ p2w,
    const float* __restrict__ f_g, float* __restrict__ remR,
    float* __restrict__ c_g, float kk, float multiR)
{
    __shared__ float4 sQ[NPTS];              // rows: x,y,z, kk*|p|^2
    __shared__ float sF[NPTS];               // f_i
    const int col0 = blockIdx.x * RPB;
    const int batch = col0 >> 11;
    const float4* P1 = p1w + ((size_t)batch << 11);
    const float* F = f_g + ((size_t)batch << 11);
    for (int i = threadIdx.x; i < NPTS; i += BLOCK) {
        float4 q = P1[i];
        q.w = kk * (q.x*q.x + q.y*q.y + q.z*q.z);
        sQ[i] = q;
        sF[i] = F[i];
    }
    __syncthreads();
    const int lane = threadIdx.x & 63;
    const int wave = threadIdx.x >> 6;
    const int c0 = col0 + wave * RPW;
    RowPair rp[4];
#pragma unroll
    for (int k = 0; k < 4; ++k)
        rp[k] = mk_pair(with_sq(p2w[c0 + 2*k]), with_sq(p2w[c0 + 2*k + 1]), kk);
    v2 aS[4];
#pragma unroll
    for (int k = 0; k < 4; ++k) aS[k] = sp(0.f);
    float4 qc = sQ[lane];
    float fc = sF[lane];
#pragma unroll 1
    for (int it = 0; it < NPTS / 64; ++it) {
        int jn = (lane + (it + 1) * 64) & 2047;
        float4 qn = sQ[jn];
        float fn = sF[jn];
        v2 qb2 = sp(qc.w);
        v2 w2 = sp(fc);
#pragma unroll
        for (int k = 0; k < 4; ++k) {
            v2 t = term(rp[k], qc.x, qc.y, qc.z, qb2);
            aS[k] = fma2(w2, v2{fexp2(t.x), fexp2(t.y)}, aS[k]);
        }
        qc = qn; fc = fn;
    }
    float sv[RPW];
#pragma unroll
    for (int k = 0; k < 4; ++k) {
        sv[2*k]   = xreduce(aS[k].x);
        sv[2*k+1] = xreduce(aS[k].y);
    }
    if (lane == 0) {
#pragma unroll
        for (int r = 0; r < RPW; ++r) {
            int gj = c0 + r;
            float R = FIRST ? multiR : remR[gj];
            float colsum = R * sv[r];
            float rr = fminf(R / (1e-9f + colsum), 1.0f);
            c_g[gj] = R * rr;
            remR[gj] = fmaxf(R - colsum * rr, 0.f);
        }
    }
}

// Rows pass: C_t fused with A_{t+1}. LDS 48KB.
// MODE 0: t=9 (kk=0): C only, e==1, plain sqrt(d2), no exp.
// MODE 1: t<8: kp=kk_{t+1}; C-weight=e1^4; aA += rw*e1.
// MODE 2: t=8: kp=kk_8; C-weight=e1; aA = sum rw (hoisted).
template <int MODE, bool FIRSTC>
__global__ __launch_bounds__(BLOCK) void k_CA(
    const float4* __restrict__ p1w, const float4* __restrict__ p2w,
    float* __restrict__ f_g, const float* __restrict__ c_g,
    const float* __restrict__ remR, float* __restrict__ remL,
    float* __restrict__ costrow, float kp, float rsqkp, float multiL)
{
    __shared__ float4 sQ[NPTS];              // x,y,z, kp*|q|^2
    __shared__ float2 sCR[NPTS];             // c, r
    const int row0 = blockIdx.x * RPB;
    const int batch = row0 >> 11;
    const float4* P2 = p2w + ((size_t)batch << 11);
    const float* C = c_g + ((size_t)batch << 11);
    const float* R = remR + ((size_t)batch << 11);
    for (int j = threadIdx.x; j < NPTS; j += BLOCK) {
        float4 q = P2[j];
        q.w = kp * (q.x*q.x + q.y*q.y + q.z*q.z);
        sQ[j] = q;
        sCR[j] = make_float2(C[j], MODE ? R[j] : 0.f);
    }
    __syncthreads();
    const int lane = threadIdx.x & 63;
    const int wave = threadIdx.x >> 6;
    const int r0 = row0 + wave * RPW;

    if (MODE == 0) {
        float px[RPW], py[RPW], pz[RPW], aU[RPW];
#pragma unroll
        for (int r = 0; r < RPW; ++r) {
            float4 q = p1w[r0 + r];
            px[r] = q.x; py[r] = q.y; pz[r] = q.z; aU[r] = 0.f;
        }
        float aT = 0.f;
        float4 qc = sQ[lane];
        float cwc = sCR[lane].x;
#pragma unroll 1
        for (int it = 0; it < NPTS / 64; ++it) {
            int jn = (lane + (it + 1) * 64) & 2047;
            float4 qn = sQ[jn];
            float cwn = sCR[jn].x;
            aT += cwc;
#pragma unroll
            for (int r = 0; r < RPW; ++r) {
                float dx = px[r]-qc.x, dy = py[r]-qc.y, dz = pz[r]-qc.z;
                float d2 = fmaf(dx, dx, fmaf(dy, dy, dz * dz));
                aU[r] = fmaf(cwc, fsqrt(d2), aU[r]);
            }
            qc = qn; cwc = cwn;
        }
        float tt = xreduce(aT);
#pragma unroll
        for (int r = 0; r < RPW; ++r) {
            float uu = xreduce(aU[r]);
            if (lane == 0) {
                int gi = r0 + r;
                float fi = f_g[gi];
                remL[gi] = fmaxf(remL[gi] - fi * tt, 0.f);
                costrow[gi] += fi * uu;
            }
        }
        return;
    }

    RowPair rp[4];
    float fiv[RPW];
#pragma unroll
    for (int k = 0; k < 4; ++k) {
        rp[k] = mk_pair(with_sq(p1w[r0 + 2*k]), with_sq(p1w[r0 + 2*k + 1]), kp);
        fiv[2*k] = f_g[r0 + 2*k]; fiv[2*k+1] = f_g[r0 + 2*k + 1];
    }
    v2 aT[4], aU[4], aA[4];
#pragma unroll
    for (int k = 0; k < 4; ++k) { aT[k] = sp(0.f); aU[k] = sp(0.f); aA[k] = sp(0.f); }
    float aAs = 0.f;
    float4 qc = sQ[lane];
    float2 crc = sCR[lane];
#pragma unroll 1
    for (int it = 0; it < NPTS / 64; ++it) {
        int jn = (lane + (it + 1) * 64) & 2047;
        float4 qn = sQ[jn];
        float2 crn = sCR[jn];
        v2 qb2 = sp(qc.w);
        float cw = crc.x, rw = crc.y;
        if (MODE == 2) aAs += rw;
#pragma unroll
        for (int k = 0; k < 4; ++k) {
            v2 t = term(rp[k], qc.x, qc.y, qc.z, qb2);
            v2 e = v2{fexp2(t.x), fexp2(t.y)};
            v2 eC;
            if (MODE == 1) { v2 e2 = e * e; eC = sp(cw) * (e2 * e2); }
            else           { eC = sp(cw) * e; }
            aT[k] += eC;
            v2 st = v2{fsqrt(fabsf(t.x)), fsqrt(fabsf(t.y))};
            aU[k] = fma2(eC, st, aU[k]);
            if (MODE == 1) aA[k] = fma2(sp(rw), e, aA[k]);
        }
        qc = qn; crc = crn;
    }
    float aas = (MODE == 2) ? xreduce(aAs) : 0.f;
    float tt[RPW], uu[RPW], aav[RPW];
#pragma unroll
    for (int k = 0; k < 4; ++k) {
        tt[2*k]   = xreduce(aT[k].x);  tt[2*k+1] = xreduce(aT[k].y);
        uu[2*k]   = xreduce(aU[k].x);  uu[2*k+1] = xreduce(aU[k].y);
        if (MODE == 1) { aav[2*k] = xreduce(aA[k].x); aav[2*k+1] = xreduce(aA[k].y); }
        else           { aav[2*k] = aas; aav[2*k+1] = aas; }
    }
    if (lane == 0) {
#pragma unroll
        for (int r = 0; r < RPW; ++r) {
            int gi = r0 + r;
            float rl0 = FIRSTC ? multiL : remL[gi];
            float rl = fmaxf(rl0 - fiv[r] * tt[r], 0.f);
            costrow[gi] = (FIRSTC ? 0.f : costrow[gi]) + fiv[r] * uu[r] * rsqkp;
            remL[gi] = rl;
            f_g[gi] = rl / (1e-9f + aav[r]);
        }
    }
}

__global__ void k_cost(const float* __restrict__ costrow,
                       float* __restrict__ out, int n) {
    __shared__ float wsum[BLOCK / 64];
    const float* cr = costrow + (size_t)blockIdx.x * n;
    float s = 0.f;
    for (int i = threadIdx.x; i < n; i += BLOCK) s += cr[i];
    s = xreduce(s);
    int wave = threadIdx.x >> 6, lane = threadIdx.x & 63;
    if (lane == 0) wsum[wave] = s;
    __syncthreads();
    if (threadIdx.x == 0) {
        float t = 0.f;
#pragma unroll
        for (int w = 0; w < BLOCK / 64; ++w) t += wsum[w];
        out[blockIdx.x] = t;
    }
}

extern "C" void kernel_launch(void* const* d_in, const int* in_sizes, int n_in,
                              void* d_out, int out_size, void* d_ws, size_t ws_size,
                              hipStream_t stream) {
    const float* xyz1 = (const float*)d_in[0];
    const float* xyz2 = (const float*)d_in[1];
    float* out = (float*)d_out;
    const int b = out_size;                 // 8
    const int n = in_sizes[0] / (3 * b);    // 2048
    const int m = in_sizes[1] / (3 * b);    // 2048
    const int bn = b * n, bm = b * m;

    float4* p1w = (float4*)d_ws;            // bn
    float4* p2w = p1w + bn;                 // bm
    float* remL    = (float*)(p2w + bm);    // bn
    float* remR    = remL + bn;             // bm
    float* f       = remR + bm;             // bn
    float* c       = f + bn;                // bm
    float* costrow = c + bm;                // bn

    const float multiL = (float)((m / n > 1) ? (m / n) : 1);
    const float multiR = (float)((n / m > 1) ? (n / m) : 1);

    dim3 g(bn / RPB), blk(BLOCK);           // 512 blocks
    const float kk0 = -16384.f * L2E;       // level -4^7
    k_A<<<g, blk, 0, stream>>>(xyz1, xyz2, p1w, p2w, f, kk0, multiL, multiR);

    for (int t = 0; t < 10; ++t) {
        const float lvl = (t < 9) ? -exp2f(2.f * (float)(7 - t)) : 0.f;  // -4^(7-t)
        const float kk = lvl * L2E;
        if (t == 0)
            k_B<true><<<g, blk, 0, stream>>>(p1w, p2w, f, remR, c, kk, multiR);
        else
            k_B<false><<<g, blk, 0, stream>>>(p1w, p2w, f, remR, c, kk, multiR);

        if (t < 8) {
            const float kp = kk * 0.25f;                 // = kk_{t+1}
            const float rsq = 1.f / sqrtf(-kp);
            if (t == 0)
                k_CA<1, true><<<g, blk, 0, stream>>>(p1w, p2w, f, c, remR, remL,
                                                     costrow, kp, rsq, multiL);
            else
                k_CA<1, false><<<g, blk, 0, stream>>>(p1w, p2w, f, c, remR, remL,
                                                      costrow, kp, rsq, multiL);
        } else if (t == 8) {
            const float kp = -0.25f * L2E;               // kk_8
            const float rsq = 1.f / sqrtf(0.25f * L2E);
            k_CA<2, false><<<g, blk, 0, stream>>>(p1w, p2w, f, c, remR, remL,
                                                  costrow, kp, rsq, multiL);
        } else {
            k_CA<0, false><<<g, blk, 0, stream>>>(p1w, p2w, f, c, remR, remL,
                                                  costrow, 0.f, 1.f, multiL);
        }
    }
    k_cost<<<dim3(b), blk, 0, stream>>>(costrow, out, n);
}

// Round 13
// 275.799 us; speedup vs baseline: 1.0595x; 1.0595x over previous
//
#include <hip/hip_runtime.h>
#include <math.h>

// approxmatch EMD (Fan et al.) — b=8, n=m=2048, f32.
// R13 = R11 + exact instruction cuts:
//  - B_9 (kk=0): e==1 -> s_j = sum_i f_i = const per batch -> tiny kernel.
//  - B_t: f folded into exponent: f*exp2(kk d2) = exp2(kk d2 + log2 f);
//    log2 f computed once per point at staging. Single b128 LDS read/iter.
//  - CA_9: remL/aT dead (nothing reads them after); k_cost fused via one
//    atomicAdd per block (out zeroed in k_B9).
// 21 dispatches: A0 | 9 x { B_t ; CA_t } | B9 | C9.
//   A: f_i = multiL/(1e-9 + multiR*sum_j e(kk))          [level 0]
//   B: s_j = sum_i f_i e(kk); colsum=R s; rr=min(R/(1e-9+colsum),1);
//      c=R rr; R' = max(R-colsum rr,0)
//   C: t_i=sum_j c e; u_i=sum_j c e sqrt(d2);
//      remL'=max(remL-f t,0); cost+=f u
// CA_t fuses C_t with A_{t+1} (level_t = 4*level_{t+1} exact for t<8):
// e1=exp2(kk_{t+1} d2) serves C (e1^4) and A (e1).
// Folded exponent: kk*d2 = kk|p|^2 + kk|q|^2 - 2kk(p.q);
// sqrt(d2)=sqrt(|kk d2|)/sqrt(|kk|) hoisted. Rows packed in v2 pairs.

#define NPTS 2048
#define BLOCK 256
#define RPB 16               // rows per block -> 128 blocks/batch, grid 1024
#define L2E 1.4426950408889634f

typedef float v2 __attribute__((ext_vector_type(2)));

__device__ __forceinline__ float fexp2(float x) { return __builtin_amdgcn_exp2f(x); }
__device__ __forceinline__ float fsqrt(float x) { return __builtin_amdgcn_sqrtf(x); }
__device__ __forceinline__ float flog2(float x) { return __builtin_amdgcn_logf(x); }
__device__ __forceinline__ v2 fma2(v2 a, v2 b, v2 c) { return __builtin_elementwise_fma(a, b, c); }
__device__ __forceinline__ v2 sp(float a) { v2 r; r.x = a; r.y = a; return r; }
__device__ __forceinline__ float xreduce(float v) {
#pragma unroll
    for (int off = 1; off < 64; off <<= 1) v += __shfl_xor(v, off, 64);
    return v;
}

struct RowPair { v2 pa, px, py, pz; };
__device__ __forceinline__ RowPair mk_pair(float4 a, float4 b, float kp) {
    RowPair r;
    r.pa = v2{kp * a.w, kp * b.w};
    r.px = v2{-2.f*kp*a.x, -2.f*kp*b.x};
    r.py = v2{-2.f*kp*a.y, -2.f*kp*b.y};
    r.pz = v2{-2.f*kp*a.z, -2.f*kp*b.z};
    return r;
}
__device__ __forceinline__ v2 term(const RowPair& r, float qx, float qy, float qz, v2 qb2) {
    return fma2(r.px, sp(qx), fma2(r.py, sp(qy), fma2(r.pz, sp(qz), r.pa + qb2)));
}
__device__ __forceinline__ float4 with_sq(float4 p) {
    p.w = p.x*p.x + p.y*p.y + p.z*p.z;
    return p;
}

// Level-0 rows pass; packs this block's 16 rows/cols into float4 arrays.
__global__ __launch_bounds__(BLOCK) void k_A(
    const float* __restrict__ xyz1, const float* __restrict__ xyz2,
    float4* __restrict__ p1w, float4* __restrict__ p2w,
    float* __restrict__ f_g, float kk, float multiL, float multiR)
{
    __shared__ float4 sQ[NPTS];              // x,y,z, kk*|q|^2
    const int row0 = blockIdx.x * RPB;
    const int batch = row0 >> 11;
    const int rloc = row0 & 2047;
    const float* g1 = xyz1 + (size_t)batch * NPTS * 3;
    const float* g2 = xyz2 + (size_t)batch * NPTS * 3;
    if (threadIdx.x < RPB) {
        int i = rloc + threadIdx.x;
        p1w[((size_t)batch << 11) + i] = make_float4(g1[3*i], g1[3*i+1], g1[3*i+2], 0.f);
    } else if (threadIdx.x < 2 * RPB) {
        int i = rloc + threadIdx.x - RPB;
        p2w[((size_t)batch << 11) + i] = make_float4(g2[3*i], g2[3*i+1], g2[3*i+2], 0.f);
    }
    for (int j = threadIdx.x; j < NPTS; j += BLOCK) {
        float qx = g2[3*j], qy = g2[3*j+1], qz = g2[3*j+2];
        sQ[j] = make_float4(qx, qy, qz, kk * (qx*qx + qy*qy + qz*qz));
    }
    __syncthreads();
    const int lane = threadIdx.x & 63;
    const int wave = threadIdx.x >> 6;
    const int r0 = row0 + wave * 4;
    RowPair rA, rB;
    {
        const float* p = g1 + 3 * (r0 & 2047);
        float4 p0 = make_float4(p[0], p[1], p[2], p[0]*p[0]+p[1]*p[1]+p[2]*p[2]);
        float4 p1 = make_float4(p[3], p[4], p[5], p[3]*p[3]+p[4]*p[4]+p[5]*p[5]);
        float4 p2 = make_float4(p[6], p[7], p[8], p[6]*p[6]+p[7]*p[7]+p[8]*p[8]);
        float4 p3 = make_float4(p[9], p[10], p[11], p[9]*p[9]+p[10]*p[10]+p[11]*p[11]);
        rA = mk_pair(p0, p1, kk); rB = mk_pair(p2, p3, kk);
    }
    v2 aSA = sp(0.f), aSB = sp(0.f);
#pragma unroll 8
    for (int j = lane; j < NPTS; j += 64) {
        float4 q = sQ[j];
        v2 qb2 = sp(q.w);
        v2 tA = term(rA, q.x, q.y, q.z, qb2);
        v2 tB = term(rB, q.x, q.y, q.z, qb2);
        aSA += v2{fexp2(tA.x), fexp2(tA.y)};
        aSB += v2{fexp2(tB.x), fexp2(tB.y)};
    }
    float sv[4] = {xreduce(aSA.x), xreduce(aSA.y), xreduce(aSB.x), xreduce(aSB.y)};
    if (lane == 0) {
#pragma unroll
        for (int r = 0; r < 4; ++r)
            f_g[r0 + r] = multiL / (1e-9f + multiR * sv[r]);
    }
}

// Cols pass, t<=8. LDS 32KB (log2(f) folded into sQ.w).
template <bool FIRST>
__global__ __launch_bounds__(BLOCK) void k_B(
    const float4* __restrict__ p1w, const float4* __restrict__ p2w,
    const float* __restrict__ f_g, float* __restrict__ remR,
    float* __restrict__ c_g, float kk, float multiR)
{
    __shared__ float4 sQ[NPTS];              // rows: x,y,z, kk*|p|^2 + log2(f)
    const int col0 = blockIdx.x * RPB;
    const int batch = col0 >> 11;
    const float4* P1 = p1w + ((size_t)batch << 11);
    const float* F = f_g + ((size_t)batch << 11);
    for (int i = threadIdx.x; i < NPTS; i += BLOCK) {
        float4 q = P1[i];
        q.w = kk * (q.x*q.x + q.y*q.y + q.z*q.z) + flog2(F[i]);
        sQ[i] = q;
    }
    __syncthreads();
    const int lane = threadIdx.x & 63;
    const int wave = threadIdx.x >> 6;
    const int c0 = col0 + wave * 4;
    RowPair rA, rB;
    {
        float4 q0 = with_sq(p2w[c0]),     q1 = with_sq(p2w[c0+1]);
        float4 q2 = with_sq(p2w[c0+2]),   q3 = with_sq(p2w[c0+3]);
        rA = mk_pair(q0, q1, kk); rB = mk_pair(q2, q3, kk);
    }
    v2 aSA = sp(0.f), aSB = sp(0.f);
#pragma unroll 8
    for (int i = lane; i < NPTS; i += 64) {
        float4 p = sQ[i];
        v2 qb2 = sp(p.w);
        v2 tA = term(rA, p.x, p.y, p.z, qb2);
        v2 tB = term(rB, p.x, p.y, p.z, qb2);
        aSA += v2{fexp2(tA.x), fexp2(tA.y)};
        aSB += v2{fexp2(tB.x), fexp2(tB.y)};
    }
    float sv[4] = {xreduce(aSA.x), xreduce(aSA.y), xreduce(aSB.x), xreduce(aSB.y)};
    if (lane == 0) {
#pragma unroll
        for (int r = 0; r < 4; ++r) {
            int gj = c0 + r;
            float R = FIRST ? multiR : remR[gj];
            float colsum = R * sv[r];
            float rr = fminf(R / (1e-9f + colsum), 1.0f);
            c_g[gj] = R * rr;
            remR[gj] = fmaxf(R - colsum * rr, 0.f);
        }
    }
}

// B_9 (kk=0): s_j = sum_i f_i (constant per batch). One block per batch.
// Also zeroes out[batch] for the fused C9 cost accumulation.
__global__ __launch_bounds__(BLOCK) void k_B9(
    const float* __restrict__ f_g, const float* __restrict__ remR,
    float* __restrict__ c_g, float* __restrict__ out)
{
    __shared__ float wsum[BLOCK / 64];
    const int batch = blockIdx.x;
    const float* F = f_g + ((size_t)batch << 11);
    float s = 0.f;
    for (int i = threadIdx.x; i < NPTS; i += BLOCK) s += F[i];
    s = xreduce(s);
    int wave = threadIdx.x >> 6, lane = threadIdx.x & 63;
    if (lane == 0) wsum[wave] = s;
    __syncthreads();
    float Ftot = (wsum[0] + wsum[1]) + (wsum[2] + wsum[3]);
    if (threadIdx.x == 0) out[batch] = 0.f;
    for (int j = threadIdx.x; j < NPTS; j += BLOCK) {
        int gj = (batch << 11) + j;
        float R = remR[gj];
        float colsum = R * Ftot;
        float rr = fminf(R / (1e-9f + colsum), 1.0f);
        c_g[gj] = R * rr;
        // remR' dead after t=9 -> not written
    }
}

// Rows pass: C_t fused with A_{t+1}, t=0..8. LDS 48KB.
// MODE 1: t<8: kp=kk_{t+1}; C-weight=e1^4; aA += rw*e1.
// MODE 2: t=8: kp=kk_8; C-weight=e1; aA = sum rw (hoisted).
template <int MODE, bool FIRSTC>
__global__ __launch_bounds__(BLOCK) void k_CA(
    const float4* __restrict__ p1w, const float4* __restrict__ p2w,
    float* __restrict__ f_g, const float* __restrict__ c_g,
    const float* __restrict__ remR, float* __restrict__ remL,
    float* __restrict__ costrow, float kp, float rsqkp, float multiL)
{
    __shared__ float4 sQ[NPTS];              // x,y,z, kp*|q|^2
    __shared__ float2 sCR[NPTS];             // c, r
    const int row0 = blockIdx.x * RPB;
    const int batch = row0 >> 11;
    const float4* P2 = p2w + ((size_t)batch << 11);
    const float* C = c_g + ((size_t)batch << 11);
    const float* R = remR + ((size_t)batch << 11);
    for (int j = threadIdx.x; j < NPTS; j += BLOCK) {
        float4 q = P2[j];
        q.w = kp * (q.x*q.x + q.y*q.y + q.z*q.z);
        sQ[j] = q;
        sCR[j] = make_float2(C[j], R[j]);
    }
    __syncthreads();
    const int lane = threadIdx.x & 63;
    const int wave = threadIdx.x >> 6;
    const int r0 = row0 + wave * 4;

    RowPair rA, rB;
    v2 fiA, fiB;
    {
        float4 p0 = with_sq(p1w[r0]),   p1 = with_sq(p1w[r0+1]);
        float4 p2 = with_sq(p1w[r0+2]), p3 = with_sq(p1w[r0+3]);
        rA = mk_pair(p0, p1, kp); rB = mk_pair(p2, p3, kp);
        fiA = v2{f_g[r0], f_g[r0+1]}; fiB = v2{f_g[r0+2], f_g[r0+3]};
    }
    v2 aTA = sp(0.f), aTB = sp(0.f), aUA = sp(0.f), aUB = sp(0.f);
    v2 aAA = sp(0.f), aAB = sp(0.f);
    float aAs = 0.f;
#pragma unroll 4
    for (int j = lane; j < NPTS; j += 64) {
        float4 q = sQ[j];
        float2 crj = sCR[j];
        v2 qb2 = sp(q.w);
        float cw = crj.x, rw = crj.y;
        v2 tA = term(rA, q.x, q.y, q.z, qb2);
        v2 tB = term(rB, q.x, q.y, q.z, qb2);
        v2 eA = v2{fexp2(tA.x), fexp2(tA.y)};
        v2 eB = v2{fexp2(tB.x), fexp2(tB.y)};
        v2 eCA, eCB;
        if (MODE == 1) {
            v2 e2A = eA * eA, e2B = eB * eB;
            eCA = sp(cw) * (e2A * e2A); eCB = sp(cw) * (e2B * e2B);
        } else {
            eCA = sp(cw) * eA; eCB = sp(cw) * eB;
        }
        aTA += eCA; aTB += eCB;
        v2 stA = v2{fsqrt(fabsf(tA.x)), fsqrt(fabsf(tA.y))};
        v2 stB = v2{fsqrt(fabsf(tB.x)), fsqrt(fabsf(tB.y))};
        aUA = fma2(eCA, stA, aUA); aUB = fma2(eCB, stB, aUB);
        if (MODE == 1) { aAA = fma2(sp(rw), eA, aAA); aAB = fma2(sp(rw), eB, aAB); }
        else           { aAs += rw; }
    }
    float aas = (MODE == 2) ? xreduce(aAs) : 0.f;
    float tt[4] = {xreduce(aTA.x), xreduce(aTA.y), xreduce(aTB.x), xreduce(aTB.y)};
    float uu[4] = {xreduce(aUA.x), xreduce(aUA.y), xreduce(aUB.x), xreduce(aUB.y)};
    float aav[4];
    if (MODE == 1) {
        aav[0] = xreduce(aAA.x); aav[1] = xreduce(aAA.y);
        aav[2] = xreduce(aAB.x); aav[3] = xreduce(aAB.y);
    } else {
        aav[0] = aav[1] = aav[2] = aav[3] = aas;
    }
    float fiv[4] = {fiA.x, fiA.y, fiB.x, fiB.y};
    if (lane == 0) {
#pragma unroll
        for (int r = 0; r < 4; ++r) {
            int gi = r0 + r;
            float rl0 = FIRSTC ? multiL : remL[gi];
            float rl = fmaxf(rl0 - fiv[r] * tt[r], 0.f);
            costrow[gi] = (FIRSTC ? 0.f : costrow[gi]) + fiv[r] * uu[r] * rsqkp;
            remL[gi] = rl;
            f_g[gi] = rl / (1e-9f + aav[r]);
        }
    }
}

// Final level (kk=0): e==1 -> u_i = sum_j c_j sqrt(d2);
// out[batch] += costrow_i + f_i*u_i  (remL/aT dead; k_cost fused).
__global__ __launch_bounds__(BLOCK) void k_C9(
    const float4* __restrict__ p1w, const float4* __restrict__ p2w,
    const float* __restrict__ f_g, const float* __restrict__ c_g,
    const float* __restrict__ costrow, float* __restrict__ out)
{
    __shared__ float4 sQ[NPTS];
    __shared__ float sC[NPTS];
    __shared__ float wsum[BLOCK / 64];
    const int row0 = blockIdx.x * RPB;
    const int batch = row0 >> 11;
    const float4* P2 = p2w + ((size_t)batch << 11);
    const float* C = c_g + ((size_t)batch << 11);
    for (int j = threadIdx.x; j < NPTS; j += BLOCK) {
        sQ[j] = P2[j];
        sC[j] = C[j];
    }
    __syncthreads();
    const int lane = threadIdx.x & 63;
    const int wave = threadIdx.x >> 6;
    const int r0 = row0 + wave * 4;
    float px[4], py[4], pz[4], aU[4];
#pragma unroll
    for (int r = 0; r < 4; ++r) {
        float4 q = p1w[r0 + r];
        px[r] = q.x; py[r] = q.y; pz[r] = q.z; aU[r] = 0.f;
    }
#pragma unroll 4
    for (int j = lane; j < NPTS; j += 64) {
        float4 q = sQ[j];
        float cw = sC[j];
#pragma unroll
        for (int r = 0; r < 4; ++r) {
            float dx = px[r]-q.x, dy = py[r]-q.y, dz = pz[r]-q.z;
            float d2 = fmaf(dx, dx, fmaf(dy, dy, dz * dz));
            aU[r] = fmaf(cw, fsqrt(d2), aU[r]);
        }
    }
    float psum = 0.f;
#pragma unroll
    for (int r = 0; r < 4; ++r) {
        float uu = xreduce(aU[r]);
        if (lane == 0) psum += costrow[r0 + r] + f_g[r0 + r] * uu;
    }
    if (lane == 0) wsum[wave] = psum;
    __syncthreads();
    if (threadIdx.x == 0)
        atomicAdd(&out[batch], (wsum[0] + wsum[1]) + (wsum[2] + wsum[3]));
}

extern "C" void kernel_launch(void* const* d_in, const int* in_sizes, int n_in,
                              void* d_out, int out_size, void* d_ws, size_t ws_size,
                              hipStream_t stream) {
    const float* xyz1 = (const float*)d_in[0];
    const float* xyz2 = (const float*)d_in[1];
    float* out = (float*)d_out;
    const int b = out_size;                 // 8
    const int n = in_sizes[0] / (3 * b);    // 2048
    const int m = in_sizes[1] / (3 * b);    // 2048
    const int bn = b * n, bm = b * m;

    float4* p1w = (float4*)d_ws;            // bn
    float4* p2w = p1w + bn;                 // bm
    float* remL    = (float*)(p2w + bm);    // bn
    float* remR    = remL + bn;             // bm
    float* f       = remR + bm;             // bn
    float* c       = f + bn;                // bm
    float* costrow = c + bm;                // bn

    const float multiL = (float)((m / n > 1) ? (m / n) : 1);
    const float multiR = (float)((n / m > 1) ? (n / m) : 1);

    dim3 g(bn / RPB), blk(BLOCK);
    const float kk0 = -16384.f * L2E;       // level -4^7
    k_A<<<g, blk, 0, stream>>>(xyz1, xyz2, p1w, p2w, f, kk0, multiL, multiR);

    for (int t = 0; t < 9; ++t) {
        const float kk = -exp2f(2.f * (float)(7 - t)) * L2E;  // level_t * log2e
        if (t == 0)
            k_B<true><<<g, blk, 0, stream>>>(p1w, p2w, f, remR, c, kk, multiR);
        else
            k_B<false><<<g, blk, 0, stream>>>(p1w, p2w, f, remR, c, kk, multiR);

        if (t < 8) {
            const float kp = kk * 0.25f;                 // = kk_{t+1}
            const float rsq = 1.f / sqrtf(-kp);
            if (t == 0)
                k_CA<1, true><<<g, blk, 0, stream>>>(p1w, p2w, f, c, remR, remL,
                                                     costrow, kp, rsq, multiL);
            else
                k_CA<1, false><<<g, blk, 0, stream>>>(p1w, p2w, f, c, remR, remL,
                                                      costrow, kp, rsq, multiL);
        } else {
            const float kp = -0.25f * L2E;               // kk_8
            const float rsq = 1.f / sqrtf(0.25f * L2E);
            k_CA<2, false><<<g, blk, 0, stream>>>(p1w, p2w, f, c, remR, remL,
                                                  costrow, kp, rsq, multiL);
        }
    }
    // t = 9: trivial B (e==1) then fused cost pass.
    k_B9<<<dim3(b), blk, 0, stream>>>(f, remR, c, out);
    k_C9<<<g, blk, 0, stream>>>(p1w, p2w, f, c, costrow, out);
}